// Round 5
// baseline (2444.467 us; speedup 1.0000x reference)
//
#include <hip/hip_runtime.h>
#include <hip/hip_bf16.h>
#include <stdint.h>

typedef unsigned short u16;
typedef __attribute__((ext_vector_type(4))) float floatx4;
typedef __attribute__((ext_vector_type(8))) short bf16x8;
typedef __attribute__((ext_vector_type(8))) unsigned short u16x8;
typedef const __attribute__((address_space(1))) void gvoid;
typedef __attribute__((address_space(3))) void lvoid;
typedef __attribute__((address_space(3))) u16 lu16;

static constexpr int Mdim = 4096;   // B*S = 4*1024
static constexpr int Hdim = 5120;
static constexpr int Idim = 12288;
static constexpr float QINV = 1.0f / 127.0f;

static __device__ __forceinline__ u16 f2b(float f) {
    __hip_bfloat16 h = __float2bfloat16(f);
    return *(u16*)&h;
}

// ---- int32 -> bf16 weight conversion (values in [-127,127] are exact in bf16)
__global__ void conv_i32_to_bf16(const int* __restrict__ in, u16* __restrict__ out) {
    int idx = (blockIdx.x * 256 + threadIdx.x) * 8;
    int4 v0 = *(const int4*)(in + idx);
    int4 v1 = *(const int4*)(in + idx + 4);
    u16x8 o;
    o[0] = f2b((float)v0.x); o[1] = f2b((float)v0.y);
    o[2] = f2b((float)v0.z); o[3] = f2b((float)v0.w);
    o[4] = f2b((float)v1.x); o[5] = f2b((float)v1.y);
    o[6] = f2b((float)v1.z); o[7] = f2b((float)v1.w);
    *(u16x8*)(out + idx) = o;
}

// ---- f32 -> bf16 activation conversion
__global__ void conv_f32_to_bf16(const float* __restrict__ in, u16* __restrict__ out) {
    int idx = (blockIdx.x * 256 + threadIdx.x) * 8;
    float4 v0 = *(const float4*)(in + idx);
    float4 v1 = *(const float4*)(in + idx + 4);
    u16x8 o;
    o[0] = f2b(v0.x); o[1] = f2b(v0.y); o[2] = f2b(v0.z); o[3] = f2b(v0.w);
    o[4] = f2b(v1.x); o[5] = f2b(v1.y); o[6] = f2b(v1.z); o[7] = f2b(v1.w);
    *(u16x8*)(out + idx) = o;
}

// ============================================================================
// 256x256 bf16 GEMM, BK=32, 4-deep LDS ring, ONE barrier per K-tile.
// (R4 resubmit — round 4 failed on broker infra, no counters; source audited:
// LDS bounds exact-fit, uniform barriers, consistent vmcnt/lgkm ledger.)
//
// Theory (R3 post-mortem): R3's 8-barriers/tile resynced all waves to the
// slowest one every phase (LDS queue ~770cy + straggler MFMA tail ~300cy;
// LDS and MFMA pipes never concurrent -> 6800 cyc/64K-tile vs 2800 floor).
// This version, per 32-K tile: {stage(t+3) 4x gll; 12x asm ds_read_b128;
// lgkmcnt(4); 16 MFMA; lgkmcnt(0); 16 MFMA; vmcnt(8); s_barrier}. Waves
// free-run inside the tile (per-wave lgkm gates only) so one wave's MFMA
// overlaps another's LDS reads; the single {vmcnt(8) -> barrier} per tile is
// the only cross-wave sync (publishes: tile t+1 staged, everyone done w/ t).
// Counted vmcnt, never 0 in main loop (T4); ring: reads buf[t&3], DMA writes
// buf[(t+3)&3] - distinct mod 4, WAR-safe (t-1's readers passed the barrier).
//
// LDS row-pair layout (solves BK=32's 64B-row banking): LDS-row j (128 B,
// 8 x 16B units) holds global rows {2j, 2j+1} chunks {0..3}; unit =
// u0 ^ (j&7), u0 = (g&1)*4 + c. Read lanes (lg=k-chunk, lm=row): unit =
// ((lm&1)*4+lg) ^ (lm>>1) -> 8 consecutive lanes hit 8 distinct 16B
// bank-groups (same statistics as R3's measured-zero-conflict layout).
// DMA dest stays linear (tid*16); source pre-swizzled per m104/m173:
// thread tid sources global row 2*(tid>>3) + (u0s>>2), chunk u0s&3,
// u0s = (tid&7) ^ ((tid>>3)&7).
//
// Waves: 8 (2M x 4N), wave tile 128x64, acc[8][4] floatx4.
// MODE 0: GateBuf = bf16(silu(acc*s));  MODE 1: GateBuf *= acc*s (in place);
// MODE 2: OutF = acc*s.
// ============================================================================

#define MM(a,b,c) __builtin_amdgcn_mfma_f32_16x16x32_bf16(a, b, c, 0, 0, 0)

// 16-MFMA quadrant: 4 A-frags x b0..b3 into acc[B..B+3]
#define MFQ(B, A0,A1,A2,A3) do { \
    acc[(B)+0][0]=MM(A0,b0,acc[(B)+0][0]); acc[(B)+0][1]=MM(A0,b1,acc[(B)+0][1]); \
    acc[(B)+0][2]=MM(A0,b2,acc[(B)+0][2]); acc[(B)+0][3]=MM(A0,b3,acc[(B)+0][3]); \
    acc[(B)+1][0]=MM(A1,b0,acc[(B)+1][0]); acc[(B)+1][1]=MM(A1,b1,acc[(B)+1][1]); \
    acc[(B)+1][2]=MM(A1,b2,acc[(B)+1][2]); acc[(B)+1][3]=MM(A1,b3,acc[(B)+1][3]); \
    acc[(B)+2][0]=MM(A2,b0,acc[(B)+2][0]); acc[(B)+2][1]=MM(A2,b1,acc[(B)+2][1]); \
    acc[(B)+2][2]=MM(A2,b2,acc[(B)+2][2]); acc[(B)+2][3]=MM(A2,b3,acc[(B)+2][3]); \
    acc[(B)+3][0]=MM(A3,b0,acc[(B)+3][0]); acc[(B)+3][1]=MM(A3,b1,acc[(B)+3][1]); \
    acc[(B)+3][2]=MM(A3,b2,acc[(B)+3][2]); acc[(B)+3][3]=MM(A3,b3,acc[(B)+3][3]); \
} while (0)

#define DSR(dst, addr, off) \
    asm volatile("ds_read_b128 %0, %1 offset:" #off : "=v"(dst) : "v"(addr))

#define LGKM(N) do { \
    asm volatile("s_waitcnt lgkmcnt(" #N ")" ::: "memory"); \
    __builtin_amdgcn_sched_barrier(0); \
} while (0)

#define VMW(N) asm volatile("s_waitcnt vmcnt(" #N ")" ::: "memory")
#define BAR()  __builtin_amdgcn_s_barrier()

template<int MODE>
__global__ __launch_bounds__(512, 2)
void gemm256(const u16* __restrict__ A, const u16* __restrict__ Bw,
             const float* __restrict__ scale, u16* __restrict__ GateBuf,
             float* __restrict__ OutF, int N, int K, int nbx)
{
    // 4 bufs x (A 16 KiB | B 16 KiB) = 128 KiB
    __shared__ __align__(16) u16 smem[65536];

    const int tid  = threadIdx.x;
    const int lane = tid & 63;
    const int wave = tid >> 6;
    const int wm = (wave >> 2) * 128;   // 2 M-waves
    const int wn = (wave & 3) * 64;     // 4 N-waves
    const int lm = lane & 15;
    const int lg = lane >> 4;

    // T1: bijective XCD swizzle (all grids here are %8==0)
    const int nwg = gridDim.x;
    const int bid = blockIdx.x;
    const int swz = (bid & 7) * (nwg >> 3) + (bid >> 3);
    const int row0 = (swz % nbx) * 256;
    const int col0 = (swz / nbx) * 256;

    const u16* Ablk = A  + (size_t)row0 * K;
    const u16* Bblk = Bw + (size_t)col0 * K;

    // stage source (pre-swizzled for linear LDS dest = tid*16B)
    const int u0s  = (tid & 7) ^ ((tid >> 3) & 7);
    const int gRow = ((tid >> 3) << 1) + (u0s >> 2);   // 0..127
    const int cOff = (u0s & 3) << 3;                   // k-elem offset
    const u16* sa_ = Ablk + (size_t)gRow * K + cOff;
    const u16* sb_ = Bblk + (size_t)gRow * K + cOff;
    const size_t rK128 = (size_t)128 * K;

    // read addresses: frag row R0=wm|wn+16i, lane row R0+lm, chunk lg:
    // j = (R0+lm)>>1 = R0/2 + (lm>>1); R0/2 % 8 == 0 so unit = u0r ^ (lm>>1)
    const unsigned sbase = (unsigned)(size_t)(lu16*)smem;
    const int jl  = lm >> 1;
    const int u0r = ((lm & 1) << 2) | lg;
    const unsigned laneRd = (unsigned)(jl * 128 + ((u0r ^ jl) << 4));
    const unsigned aRd = sbase + (unsigned)(wm * 64) + laneRd;            // +buf*32768, +i*1024
    const unsigned bRd = sbase + 16384u + (unsigned)(wn * 64) + laneRd;   // +buf*32768, +j*1024

    floatx4 acc[8][4];
    #pragma unroll
    for (int i = 0; i < 8; i++)
        #pragma unroll
        for (int j = 0; j < 4; j++)
            acc[i][j] = (floatx4){0.f, 0.f, 0.f, 0.f};

    const int nt = K >> 5;   // 160 or 384

#define STAGE(bb) do { \
    u16* dA_ = (u16*)smem + (bb) * 16384 + tid * 8; \
    u16* dB_ = dA_ + 8192; \
    __builtin_amdgcn_global_load_lds((gvoid*)sa_, (lvoid*)dA_, 16, 0, 0); \
    __builtin_amdgcn_global_load_lds((gvoid*)(sa_ + rK128), (lvoid*)(dA_ + 4096), 16, 0, 0); \
    __builtin_amdgcn_global_load_lds((gvoid*)sb_, (lvoid*)dB_, 16, 0, 0); \
    __builtin_amdgcn_global_load_lds((gvoid*)(sb_ + rK128), (lvoid*)(dB_ + 4096), 16, 0, 0); \
    sa_ += 32; sb_ += 32; \
} while (0)

// one 32-K tile: 12 asm ds_read_b128, two 16-MFMA clusters gated by partial
// lgkm waits (rule #18 sched_barrier after each), counted vmcnt, one barrier.
#define TILE(bb, WAITV, DOBAR) do { \
    const unsigned Ab = aRd + (unsigned)(bb) * 32768u; \
    const unsigned Bb = bRd + (unsigned)(bb) * 32768u; \
    bf16x8 b0, b1, b2, b3, a0, a1, a2, a3, a4, a5, a6, a7; \
    DSR(b0, Bb, 0); DSR(b1, Bb, 1024); DSR(b2, Bb, 2048); DSR(b3, Bb, 3072); \
    DSR(a0, Ab, 0); DSR(a1, Ab, 1024); DSR(a2, Ab, 2048); DSR(a3, Ab, 3072); \
    DSR(a4, Ab, 4096); DSR(a5, Ab, 5120); DSR(a6, Ab, 6144); DSR(a7, Ab, 7168); \
    LGKM(4);                 /* oldest 8 (b0-3,a0-3) landed */ \
    __builtin_amdgcn_s_setprio(1); \
    MFQ(0, a0, a1, a2, a3); \
    LGKM(0);                 /* a4-7 landed */ \
    MFQ(4, a4, a5, a6, a7); \
    __builtin_amdgcn_s_setprio(0); \
    WAITV; \
    if (DOBAR) __builtin_amdgcn_s_barrier(); \
} while (0)

    // prologue: stage tiles 0,1,2 (12 loads); wait tile0 (counted), publish
    STAGE(0); STAGE(1); STAGE(2);
    VMW(8);
    BAR();

    int t = 0;
    for (; t < nt - 3; ++t) {
        STAGE((t + 3) & 3);
        __builtin_amdgcn_sched_barrier(0);
        // vmcnt ledger at tile end: outstanding = t+1,t+2,t+3 stages (12)
        // -> vmcnt(8) retires t+1 (needed next tile). Never 0 (T4).
        TILE(t & 3, VMW(8), 1);
    }
    // drain: outstanding 8 -> 4 -> 0
    TILE((nt - 3) & 3, VMW(4), 1);
    TILE((nt - 2) & 3, VMW(0), 1);
    TILE((nt - 1) & 3, (void)0, 0);

#undef TILE
#undef STAGE

    // epilogue: C/D layout col=lane&15, row=(lane>>4)*4+reg   [m89-verified]
    const int ln = lane & 15;
    const int rq = (lane >> 4) * 4;
    #pragma unroll
    for (int j = 0; j < 4; j++) {
        const int col = col0 + wn + j * 16 + ln;
        const float s = scale[col] * QINV;
        #pragma unroll
        for (int i = 0; i < 8; i++) {
            const int rowb = row0 + wm + i * 16 + rq;
            #pragma unroll
            for (int r = 0; r < 4; r++) {
                const size_t idx = (size_t)(rowb + r) * N + col;
                float v = acc[i][j][r] * s;
                if (MODE == 0) {
                    float g = v / (1.0f + __expf(-v));   // silu
                    GateBuf[idx] = f2b(g);
                } else if (MODE == 1) {
                    u16 gu = GateBuf[idx];
                    float g = __bfloat162float(*(__hip_bfloat16*)&gu);
                    GateBuf[idx] = f2b(g * v);
                } else {
                    OutF[idx] = v;
                }
            }
        }
    }
}

extern "C" void kernel_launch(void* const* d_in, const int* in_sizes, int n_in,
                              void* d_out, int out_size, void* d_ws, size_t ws_size,
                              hipStream_t stream)
{
    const float* x  = (const float*)d_in[0];
    const int*   wg = (const int*)d_in[1];
    const float* sg = (const float*)d_in[2];
    const int*   wu = (const int*)d_in[3];
    const float* su = (const float*)d_in[4];
    const int*   wd = (const int*)d_in[5];
    const float* sd = (const float*)d_in[6];
    float* out = (float*)d_out;

    char* ws = (char*)d_ws;
    u16* xb   = (u16*)ws;                                        // 4096*5120 bf16   (42 MB)
    u16* wb   = (u16*)(ws + 41943040);                           // 62914560 bf16    (126 MB, reused 3x)
    u16* gate = (u16*)(ws + 41943040 + 125829120);               // 4096*12288 bf16  (100 MB, gate then h)

    conv_f32_to_bf16<<<10240, 256, 0, stream>>>(x, xb);

    // gate = silu((x @ Wg^T) * sg/127)
    conv_i32_to_bf16<<<30720, 256, 0, stream>>>(wg, wb);
    gemm256<0><<<(Mdim / 256) * (Idim / 256), 512, 0, stream>>>(
        xb, wb, sg, gate, nullptr, Idim, Hdim, Mdim / 256);

    // h = gate * ((x @ Wu^T) * su/127)   (in-place over gate)
    conv_i32_to_bf16<<<30720, 256, 0, stream>>>(wu, wb);
    gemm256<1><<<(Mdim / 256) * (Idim / 256), 512, 0, stream>>>(
        xb, wb, su, gate, nullptr, Idim, Hdim, Mdim / 256);

    // out = (h @ Wd^T) * sd/127
    conv_i32_to_bf16<<<30720, 256, 0, stream>>>(wd, wb);
    gemm256<2><<<(Mdim / 256) * (Hdim / 256), 512, 0, stream>>>(
        gate, wb, sd, nullptr, out, Hdim, Idim, Mdim / 256);
}